// Round 1
// baseline (525.676 us; speedup 1.0000x reference)
//
#include <hip/hip_runtime.h>
#include <hip/hip_cooperative_groups.h>

namespace cg = cooperative_groups;

// Problem constants (from reference)
#define BB      4096
#define EE      128
#define MM      8
#define NSTEPS  3
#define HH      256
#define CC      16

#define TS      16                    // samples per block tile (MFMA M-tile)
#define FB      1024                  // ushorts per weight frag-block (512 hi + 512 lo)

// frag-block ranges in wf:
//   W_in  : (m*8+nt)*4+kc            -> [0,256)
//   W_bias: 256 + (m*8+nt)*4+kc      -> [256,512)
//   W_f   : 512 + (m*8+nt)*8+kc      -> [512,1024)
//   W1    : 1024 + nt*4+kc (nt<16)   -> [1024,1088)
//   W2    : 1088 + kc      (kc<8)    -> [1088,1096)
#define NFRAGBLK 1096

#define CAP     4096                  // perm slots per (t,m) bucket (worst case safe)
#define GRIDN   256                   // cooperative grid: 1 block/CU guaranteed co-resident
#define NV0     (NFRAGBLK + 512)      // phase-0 virtual blocks: 1096 weight + 512 gather

typedef __attribute__((ext_vector_type(8))) short  bf16x8;
typedef __attribute__((ext_vector_type(4))) float  f32x4;

__device__ __forceinline__ unsigned short bf16_rn(float v) {
    unsigned u = __float_as_uint(v);
    return (unsigned short)((u + 0x7FFFu + ((u >> 16) & 1u)) >> 16);
}
__device__ __forceinline__ float bf16_f(unsigned short h) {
    return __uint_as_float(((unsigned)h) << 16);
}
__device__ __forceinline__ void split8(const float* v, bf16x8& hi, bf16x8& lo) {
    #pragma unroll
    for (int i = 0; i < 8; i++) {
        unsigned short h = bf16_rn(v[i]);
        hi[i] = (short)h;
        lo[i] = (short)bf16_rn(v[i] - bf16_f(h));
    }
}
__device__ __forceinline__ void split1(float v, unsigned short& h, unsigned short& l) {
    h = bf16_rn(v);
    l = bf16_rn(v - bf16_f(h));
}
#define MFMA(a,b,c) __builtin_amdgcn_mfma_f32_16x16x32_bf16((a),(b),(c),0,0,0)
__device__ __forceinline__ f32x4 mfma3(bf16x8 ah, bf16x8 al, bf16x8 bh, bf16x8 bl, f32x4 c) {
    c = MFMA(ah, bh, c);
    c = MFMA(ah, bl, c);
    c = MFMA(al, bh, c);
    return c;
}

// ---------------------------------------------------------------------------
// One persistent kernel, 6 phases:
//   0: weight convert + embedding gather-split (+ block0 zeroes cnt)
//   1: ballot-aggregated atomic scatter into fixed-capacity buckets
//   2..4: recurrent step t = ph-2 (block->bucket map derived from cnt on the fly)
//   5: head (x W1 -> relu -> W2 + b2)
// coop=1: phases run in one cooperative launch with grid.sync() between them.
// coop=0: caller launches one phase per kernel (stream order = the sync).
// ---------------------------------------------------------------------------
__global__ __launch_bounds__(512, 2) void mega_kernel(
    int ph_lo, int ph_hi, int coop,
    const int*   __restrict__ entity_ids, const int* __restrict__ module_ids,
    const float* __restrict__ embedding,
    const float* __restrict__ W_in,  const float* __restrict__ b_in,
    const float* __restrict__ W_bias,const float* __restrict__ b_bias,
    const float* __restrict__ W_f,   const float* __restrict__ b_f,
    const float* __restrict__ W1,    const float* __restrict__ b1v,
    const float* __restrict__ W2,    const float* __restrict__ b2,
    float* __restrict__ out,
    int* __restrict__ cnt, int* __restrict__ perm,
    unsigned short* __restrict__ wf,
    unsigned short* __restrict__ x0h, unsigned short* __restrict__ x0l,
    unsigned short* __restrict__ xsh, unsigned short* __restrict__ xsl,
    unsigned short* __restrict__ ebh, unsigned short* __restrict__ ebl)
{
    const int tid  = threadIdx.x;
    const int bx   = blockIdx.x, gsz = gridDim.x;
    const int lane = tid & 63, wave = tid >> 6;
    const int row16 = lane & 15, quad = lane >> 4;

    __shared__ __align__(16) unsigned short hfh[8][512]; // h, A-frag-linear, hi
    __shared__ __align__(16) unsigned short hfl[8][512]; // lo
    __shared__ int   sids[TS];
    __shared__ float red[8][TS][CC];

    cg::grid_group gg = cg::this_grid();

    for (int ph = ph_lo; ph <= ph_hi; ph++) {
        if (ph == 0) {
            // ---- zero bucket counters (tiny; done before anyone reads them) ----
            if (bx == 0 && tid < NSTEPS*MM) cnt[tid] = 0;
            for (int vb = bx; vb < NV0; vb += gsz) {
                if (vb < NFRAGBLK) {
                    // ---- weight convert (B-fragment-linear, hi/lo split) ----
                    unsigned short* dhi = wf + (size_t)vb * FB;
                    unsigned short* dlo = dhi + 512;
                    const int el = tid;                       // 512 elems, 1/thread
                    const int ln = el >> 3, j = el & 7;
                    const int krel = ((ln >> 4) << 3) + j;    // 0..31
                    const int nrel = ln & 15;
                    float v;
                    if (vb < 512) {
                        const int bb = vb & 255;
                        const int kc = bb & 3, nt = (bb >> 2) & 7, m = bb >> 5;
                        const float* src = (vb < 256 ? W_in : W_bias) + (size_t)m * EE * EE;
                        v = src[(size_t)(kc*32 + krel) * EE + nt*16 + nrel];
                    } else if (vb < 1024) {
                        const int bb = vb - 512;
                        const int kc = bb & 7, nt = (bb >> 3) & 7, m = bb >> 6;
                        v = W_f[(size_t)m * 2*EE*EE + (size_t)(kc*32 + krel) * EE + nt*16 + nrel];
                    } else if (vb < 1088) {
                        const int bb = vb - 1024;
                        const int kc = bb & 3, nt = bb >> 2;
                        v = W1[(size_t)(kc*32 + krel) * HH + nt*16 + nrel];
                    } else {
                        const int kc = vb - 1088;
                        v = W2[(size_t)(kc*32 + krel) * CC + nrel];
                    }
                    split1(v, dhi[el], dlo[el]);
                } else {
                    // ---- embedding gather + split: 32 rows per vblock ----
                    const int u = vb - NFRAGBLK;              // 0..511
                    const int rloc = tid >> 4, cpart = tid & 15;
                    const int rglob = u*32 + rloc;            // 0..16383
                    const int g = rglob >> 12;                // 0=x0, 1..3=bias step g-1
                    const int s = rglob & (BB-1);
                    const int eid = entity_ids[s*(NSTEPS+1) + g];
                    const float* src = embedding + (size_t)eid*EE + cpart*8;
                    float vv[8];
                    *(float4*)(vv)     = *(const float4*)(src);
                    *(float4*)(vv + 4) = *(const float4*)(src + 4);
                    bf16x8 hi, lo;
                    split8(vv, hi, lo);
                    unsigned short* dh = (g == 0 ? x0h : ebh + (size_t)(g-1)*BB*EE) + (size_t)s*EE + cpart*8;
                    unsigned short* dl = (g == 0 ? x0l : ebl + (size_t)(g-1)*BB*EE) + (size_t)s*EE + cpart*8;
                    *(bf16x8*)dh = hi;
                    *(bf16x8*)dl = lo;
                }
            }
        } else if (ph == 1) {
            // ---- scatter: wave-aggregated atomic bucket assignment ----
            // 12288 items; wave-uniform t (4096 % 64 == 0).
            for (int vb = bx; vb < (NSTEPS*BB)/512; vb += gsz) {
                const int gid = vb*512 + tid;
                const int t = gid >> 12, s = gid & (BB-1);
                const int m = module_ids[s*NSTEPS + t];
                unsigned long long mybal = 0ull, lanebal = 0ull;
                #pragma unroll
                for (int k = 0; k < MM; k++) {
                    const unsigned long long bk = __ballot(m == k);
                    if (m == k)    mybal   = bk;   // static index: cndmask, no scratch
                    if (lane == k) lanebal = bk;
                }
                int base = 0;
                if (lane < MM) base = atomicAdd(&cnt[t*MM + lane], __popcll(lanebal));
                const int mybase = __shfl(base, m);
                const unsigned long long below = (1ull << lane) - 1ull;
                const int rank = __popcll(mybal & below);
                perm[((t*MM + m) << 12) + mybase + rank] = s;
            }
        } else if (ph <= 4) {
            // ---- recurrent step t ----
            const int t = ph - 2;
            int creg[8];
            #pragma unroll
            for (int k = 0; k < MM; k++) creg[k] = cnt[t*MM + k];
            int NB = 0;
            #pragma unroll
            for (int k = 0; k < MM; k++) NB += (creg[k] + TS - 1) >> 4;

            for (int vb = bx; vb < NB; vb += gsz) {
                // block -> (module m, chunk) map; all indices compile-time static
                int m = -1, pref = 0, cm = 0, acc = 0;
                #pragma unroll
                for (int k = 0; k < MM; k++) {
                    const int nbk = (creg[k] + TS - 1) >> 4;
                    if (m < 0 && vb < acc + nbk) { m = k; pref = acc; cm = creg[k]; }
                    acc += nbk;
                }
                const int chunk = vb - pref;

                __syncthreads();   // protect sids/hf reuse across vb iterations
                if (tid < TS) {
                    const int sl = chunk*TS + tid;
                    sids[tid] = (sl < cm) ? perm[((t*MM + m) << 12) + sl] : -1;
                }
                __syncthreads();

                const int sA  = sids[row16];
                const int sAc = sA < 0 ? 0 : sA;

                const unsigned short* xh_p = (t == 0 ? x0h : xsh) + (size_t)sAc*EE;
                const unsigned short* xl_p = (t == 0 ? x0l : xsl) + (size_t)sAc*EE;
                const unsigned short* eh_p = ebh + (size_t)t*BB*EE + (size_t)sAc*EE;
                const unsigned short* el_p = ebl + (size_t)t*BB*EE + (size_t)sAc*EE;

                bf16x8 xh[4], xl[4], eh[4], el_[4];
                #pragma unroll
                for (int kc = 0; kc < 4; kc++) {
                    const int off = kc*32 + quad*8;
                    xh[kc]  = *(const bf16x8*)(xh_p + off);
                    xl[kc]  = *(const bf16x8*)(xl_p + off);
                    eh[kc]  = *(const bf16x8*)(eh_p + off);
                    el_[kc] = *(const bf16x8*)(el_p + off);
                }

                // phase 1: h_in, h_bi for this wave's 16 output cols
                f32x4 aci = {0.f,0.f,0.f,0.f}, acb = {0.f,0.f,0.f,0.f};
                #pragma unroll
                for (int kc = 0; kc < 4; kc++) {
                    const unsigned short* bI = wf + (size_t)((m*8 + wave)*4 + kc)*FB;
                    const unsigned short* bBp = wf + (size_t)(256 + (m*8 + wave)*4 + kc)*FB;
                    const bf16x8 wih = *(const bf16x8*)(bI + lane*8);
                    const bf16x8 wil = *(const bf16x8*)(bI + 512 + lane*8);
                    const bf16x8 wbh = *(const bf16x8*)(bBp + lane*8);
                    const bf16x8 wbl = *(const bf16x8*)(bBp + 512 + lane*8);
                    aci = mfma3(xh[kc], xl[kc], wih, wil, aci);
                    acb = mfma3(eh[kc], el_[kc], wbh, wbl, acb);
                }

                // epilogue 1: relu+bias, producer-side split, frag-linear LDS store
                {
                    const int col = wave*16 + row16;
                    const float bin = b_in [m*EE + col];
                    const float bbi = b_bias[m*EE + col];
                    #pragma unroll
                    for (int r = 0; r < 4; r++) {
                        const int row = quad*4 + r;
                        {   // h_in -> k = col
                            const float v = fmaxf(aci[r] + bin, 0.f);
                            const int k = col, kc = k >> 5;
                            const int idx = (row + 16*((k >> 3) & 3))*8 + (k & 7);
                            split1(v, hfh[kc][idx], hfl[kc][idx]);
                        }
                        {   // h_bi -> k = 128 + col
                            const float v = fmaxf(acb[r] + bbi, 0.f);
                            const int k = EE + col, kc = k >> 5;
                            const int idx = (row + 16*((k >> 3) & 3))*8 + (k & 7);
                            split1(v, hfh[kc][idx], hfl[kc][idx]);
                        }
                    }
                }
                __syncthreads();

                // phase 2: x_new = tanh(h W_f + b_f), K = 256
                f32x4 acf = {0.f,0.f,0.f,0.f};
                #pragma unroll
                for (int kc = 0; kc < 8; kc++) {
                    const bf16x8 ah = *(const bf16x8*)(&hfh[kc][lane*8]);
                    const bf16x8 al = *(const bf16x8*)(&hfl[kc][lane*8]);
                    const unsigned short* bF = wf + (size_t)(512 + (m*8 + wave)*8 + kc)*FB;
                    const bf16x8 wfh = *(const bf16x8*)(bF + lane*8);
                    const bf16x8 wfl = *(const bf16x8*)(bF + 512 + lane*8);
                    acf = mfma3(ah, al, wfh, wfl, acf);
                }
                {
                    const int col = wave*16 + row16;
                    const float bfv = b_f[m*EE + col];
                    #pragma unroll
                    for (int r = 0; r < 4; r++) {
                        const int s = sids[quad*4 + r];
                        if (s >= 0) {
                            const float v = tanhf(acf[r] + bfv);
                            unsigned short h, l;
                            split1(v, h, l);
                            xsh[(size_t)s*EE + col] = h;
                            xsl[(size_t)s*EE + col] = l;
                        }
                    }
                }
            }
        } else {
            // ---- head: 256 tiles, one per block ----
            for (int vb = bx; vb < BB/TS; vb += gsz) {
                const int sbase = vb * TS;
                __syncthreads();   // protect LDS reuse after step phase

                const unsigned short* xh_p = xsh + (size_t)(sbase + row16)*EE;
                const unsigned short* xl_p = xsl + (size_t)(sbase + row16)*EE;
                bf16x8 xh[4], xl[4];
                #pragma unroll
                for (int kc = 0; kc < 4; kc++) {
                    const int off = kc*32 + quad*8;
                    xh[kc] = *(const bf16x8*)(xh_p + off);
                    xl[kc] = *(const bf16x8*)(xl_p + off);
                }

                // h = relu(x W1 + b1): 16 n-tiles, 2 per wave
                f32x4 a1[2] = {{0.f,0.f,0.f,0.f},{0.f,0.f,0.f,0.f}};
                #pragma unroll
                for (int i = 0; i < 2; i++) {
                    const int nt = wave + 8*i;
                    #pragma unroll
                    for (int kc = 0; kc < 4; kc++) {
                        const unsigned short* bW = wf + (size_t)(1024 + nt*4 + kc)*FB;
                        const bf16x8 wh = *(const bf16x8*)(bW + lane*8);
                        const bf16x8 wl = *(const bf16x8*)(bW + 512 + lane*8);
                        a1[i] = mfma3(xh[kc], xl[kc], wh, wl, a1[i]);
                    }
                }
                #pragma unroll
                for (int i = 0; i < 2; i++) {
                    const int col = (wave + 8*i)*16 + row16;     // 0..255
                    const float b = b1v[col];
                    #pragma unroll
                    for (int r = 0; r < 4; r++) {
                        const int row = quad*4 + r;
                        const float v = fmaxf(a1[i][r] + b, 0.f);
                        const int kc = col >> 5;
                        const int idx = (row + 16*((col >> 3) & 3))*8 + (col & 7);
                        split1(v, hfh[kc][idx], hfl[kc][idx]);
                    }
                }
                __syncthreads();

                // out = h W2 + b2: K-split, wave = kc
                f32x4 a2 = {0.f,0.f,0.f,0.f};
                {
                    const int kc = wave;
                    const bf16x8 ah = *(const bf16x8*)(&hfh[kc][lane*8]);
                    const bf16x8 al = *(const bf16x8*)(&hfl[kc][lane*8]);
                    const unsigned short* bW = wf + (size_t)(1088 + kc)*FB;
                    const bf16x8 wh = *(const bf16x8*)(bW + lane*8);
                    const bf16x8 wl = *(const bf16x8*)(bW + 512 + lane*8);
                    a2 = mfma3(ah, al, wh, wl, a2);
                }
                #pragma unroll
                for (int r = 0; r < 4; r++) red[wave][quad*4 + r][row16] = a2[r];
                __syncthreads();

                if (tid < TS*CC) {
                    const int s = tid >> 4, c = tid & 15;
                    float v = b2[c];
                    #pragma unroll
                    for (int w = 0; w < 8; w++) v += red[w][s][c];
                    out[(size_t)(sbase + s)*CC + c] = v;
                }
            }
        }
        if (coop && ph < ph_hi) gg.sync();
    }
}

// ---------------------------------------------------------------------------
extern "C" void kernel_launch(void* const* d_in, const int* in_sizes, int n_in,
                              void* d_out, int out_size, void* d_ws, size_t ws_size,
                              hipStream_t stream) {
    const int*   entity_ids = (const int*)  d_in[0];
    const int*   module_ids = (const int*)  d_in[1];
    const float* embedding  = (const float*)d_in[2];
    const float* W_in   = (const float*)d_in[3];
    const float* b_in   = (const float*)d_in[4];
    const float* W_bias = (const float*)d_in[5];
    const float* b_bias = (const float*)d_in[6];
    const float* W_f    = (const float*)d_in[7];
    const float* b_f    = (const float*)d_in[8];
    const float* W1     = (const float*)d_in[9];
    const float* b1     = (const float*)d_in[10];
    const float* W2     = (const float*)d_in[11];
    const float* b2     = (const float*)d_in[12];
    float* out = (float*)d_out;

    char* ws = (char*)d_ws;
    int* cnt  = (int*)(ws + 0);                           // 96 B (zeroed in-kernel)
    int* perm = (int*)(ws + 4096);                        // 3*8*4096*4 = 384 KB
    unsigned short* wfb = (unsigned short*)(ws + (1u<<20));     // 2.25 MB
    unsigned short* x0h = (unsigned short*)(ws + (4u<<20));     // 1 MB each
    unsigned short* x0l = (unsigned short*)(ws + (5u<<20));
    unsigned short* xsh = (unsigned short*)(ws + (6u<<20));
    unsigned short* xsl = (unsigned short*)(ws + (7u<<20));
    unsigned short* ebh = (unsigned short*)(ws + (8u<<20));     // 3 MB (t-major)
    unsigned short* ebl = (unsigned short*)(ws + (11u<<20));    // 3 MB

    int lo = 0, hi = 5, coop = 1;
    void* args[] = { &lo, &hi, &coop,
                     &entity_ids, &module_ids, &embedding,
                     &W_in, &b_in, &W_bias, &b_bias, &W_f, &b_f,
                     &W1, &b1, &W2, &b2, &out,
                     &cnt, &perm, &wfb, &x0h, &x0l, &xsh, &xsl, &ebh, &ebl };
    hipError_t e = hipLaunchCooperativeKernel(
        reinterpret_cast<const void*>(mega_kernel),
        dim3(GRIDN), dim3(512), args, 0u, stream);
    if (e != hipSuccess) {
        (void)hipGetLastError();   // clear; fall back to phase-per-launch
        for (int ph = 0; ph < 6; ph++)
            mega_kernel<<<GRIDN, 512, 0, stream>>>(ph, ph, 0,
                entity_ids, module_ids, embedding,
                W_in, b_in, W_bias, b_bias, W_f, b_f, W1, b1, W2, b2, out,
                cnt, perm, wfb, x0h, x0l, xsh, xsl, ebh, ebl);
    }
}

// Round 2
// 355.160 us; speedup vs baseline: 1.4801x; 1.4801x over previous
//
#include <hip/hip_runtime.h>

// Problem constants (from reference)
#define BB      4096
#define EE      128
#define MM      8
#define NSTEPS  3
#define HH      256
#define CC      16

#define TS      16                    // samples per block tile (MFMA M-tile)
#define FB      1024                  // ushorts per weight frag-block (512 hi + 512 lo)

// frag-block ranges in wf:
//   W_in  : (m*8+nt)*4+kc            -> [0,256)
//   W_bias: 256 + (m*8+nt)*4+kc      -> [256,512)
//   W_f   : 512 + (m*8+nt)*8+kc      -> [512,1024)
//   W1    : 1024 + nt*4+kc (nt<16)   -> [1024,1088)
//   W2    : 1088 + kc      (kc<8)    -> [1088,1096)
#define NFRAGBLK 1096

#define NBMAX   (BB/TS + MM)          // 264: worst-case bucket tiles per step
#define PREP_G  512                   // gather vblocks (16384 rows / 32)
#define PREP_S  24                    // scatter vblocks (12288 items / 512)
#define PREP_GRID (NFRAGBLK + PREP_G + PREP_S)   // 1632

typedef __attribute__((ext_vector_type(8))) short  bf16x8;
typedef __attribute__((ext_vector_type(4))) float  f32x4;

__device__ __forceinline__ unsigned short bf16_rn(float v) {
    unsigned u = __float_as_uint(v);
    return (unsigned short)((u + 0x7FFFu + ((u >> 16) & 1u)) >> 16);
}
__device__ __forceinline__ float bf16_f(unsigned short h) {
    return __uint_as_float(((unsigned)h) << 16);
}
__device__ __forceinline__ void split8(const float* v, bf16x8& hi, bf16x8& lo) {
    #pragma unroll
    for (int i = 0; i < 8; i++) {
        unsigned short h = bf16_rn(v[i]);
        hi[i] = (short)h;
        lo[i] = (short)bf16_rn(v[i] - bf16_f(h));
    }
}
__device__ __forceinline__ void split1(float v, unsigned short& h, unsigned short& l) {
    h = bf16_rn(v);
    l = bf16_rn(v - bf16_f(h));
}
#define MFMA(a,b,c) __builtin_amdgcn_mfma_f32_16x16x32_bf16((a),(b),(c),0,0,0)
__device__ __forceinline__ f32x4 mfma3(bf16x8 ah, bf16x8 al, bf16x8 bh, bf16x8 bl, f32x4 c) {
    c = MFMA(ah, bh, c);
    c = MFMA(ah, bl, c);
    c = MFMA(al, bh, c);
    return c;
}

// ---------------------------------------------------------------------------
// prep: weight convert | embedding gather-split | atomic bucket scatter.
// All three parts are mutually independent; cnt must be zeroed beforehand
// (hipMemsetAsync node). Grid 1632 -> ~6 blocks/CU, enough TLP to hide the
// random-gather latency.
// ---------------------------------------------------------------------------
__global__ __launch_bounds__(512) void prep_kernel(
    const int*   __restrict__ entity_ids, const int* __restrict__ module_ids,
    const float* __restrict__ embedding,
    const float* __restrict__ W_in, const float* __restrict__ W_bias,
    const float* __restrict__ W_f,  const float* __restrict__ W1,
    const float* __restrict__ W2,
    unsigned short* __restrict__ wf,
    unsigned short* __restrict__ x0h, unsigned short* __restrict__ x0l,
    unsigned short* __restrict__ ebh, unsigned short* __restrict__ ebl,
    int* __restrict__ cnt, int* __restrict__ perm)
{
    const int vb = blockIdx.x, tid = threadIdx.x;
    if (vb < NFRAGBLK) {
        // ---- weight convert (B-fragment-linear, hi/lo split); 512 elems ----
        unsigned short* dhi = wf + (size_t)vb * FB;
        unsigned short* dlo = dhi + 512;
        const int el = tid;
        const int ln = el >> 3, j = el & 7;
        const int krel = ((ln >> 4) << 3) + j;    // 0..31
        const int nrel = ln & 15;
        float v;
        if (vb < 512) {
            const int bb = vb & 255;
            const int kc = bb & 3, nt = (bb >> 2) & 7, m = bb >> 5;
            const float* src = (vb < 256 ? W_in : W_bias) + (size_t)m * EE * EE;
            v = src[(size_t)(kc*32 + krel) * EE + nt*16 + nrel];
        } else if (vb < 1024) {
            const int bb = vb - 512;
            const int kc = bb & 7, nt = (bb >> 3) & 7, m = bb >> 6;
            v = W_f[(size_t)m * 2*EE*EE + (size_t)(kc*32 + krel) * EE + nt*16 + nrel];
        } else if (vb < 1088) {
            const int bb = vb - 1024;
            const int kc = bb & 3, nt = bb >> 2;
            v = W1[(size_t)(kc*32 + krel) * HH + nt*16 + nrel];
        } else {
            const int kc = vb - 1088;
            v = W2[(size_t)(kc*32 + krel) * CC + nrel];
        }
        split1(v, dhi[el], dlo[el]);
    } else if (vb < NFRAGBLK + PREP_G) {
        // ---- embedding gather + split: 32 rows per vblock ----
        const int u = vb - NFRAGBLK;              // 0..511
        const int rloc = tid >> 4, cpart = tid & 15;
        const int rglob = u*32 + rloc;            // 0..16383
        const int g = rglob >> 12;                // 0=x0, 1..3=bias step g-1
        const int s = rglob & (BB-1);
        const int eid = entity_ids[s*(NSTEPS+1) + g];
        const float* src = embedding + (size_t)eid*EE + cpart*8;
        float vv[8];
        *(float4*)(vv)     = *(const float4*)(src);
        *(float4*)(vv + 4) = *(const float4*)(src + 4);
        bf16x8 hi, lo;
        split8(vv, hi, lo);
        unsigned short* dh = (g == 0 ? x0h : ebh + (size_t)(g-1)*BB*EE) + (size_t)s*EE + cpart*8;
        unsigned short* dl = (g == 0 ? x0l : ebl + (size_t)(g-1)*BB*EE) + (size_t)s*EE + cpart*8;
        *(bf16x8*)dh = hi;
        *(bf16x8*)dl = lo;
    } else {
        // ---- scatter: wave-aggregated atomic bucket assignment ----
        const int u = vb - NFRAGBLK - PREP_G;     // 0..23
        const int gid = u*512 + tid;              // wave-uniform t (4096 % 64 == 0)
        const int lane = tid & 63;
        const int t = gid >> 12, s = gid & (BB-1);
        const int m = module_ids[s*NSTEPS + t];
        unsigned long long mybal = 0ull, lanebal = 0ull;
        #pragma unroll
        for (int k = 0; k < MM; k++) {
            const unsigned long long bk = __ballot(m == k);
            if (m == k)    mybal   = bk;          // static index: cndmask, no scratch
            if (lane == k) lanebal = bk;
        }
        int base = 0;
        if (lane < MM) base = atomicAdd(&cnt[t*MM + lane], __popcll(lanebal));
        const int mybase = __shfl(base, m);
        const unsigned long long below = (1ull << lane) - 1ull;
        const int rank = __popcll(mybal & below);
        perm[((t*MM + m) << 12) + mybase + rank] = s;
    }
}

// ---------------------------------------------------------------------------
// step: one recurrent step (8 waves, wave = n-tile). For the LAST step the
// classifier head (relu(x W1 + b1) W2 + b2) is fused in-block: x stays in
// registers/LDS, no xs round-trip, no separate head kernel.
// ---------------------------------------------------------------------------
__global__ __launch_bounds__(512, 2) void step_kernel(
    const int t,
    const unsigned short* __restrict__ x0h, const unsigned short* __restrict__ x0l,
    const unsigned short* __restrict__ ebh, const unsigned short* __restrict__ ebl,
    const float* __restrict__ b_in, const float* __restrict__ b_bias,
    const float* __restrict__ b_f,
    const float* __restrict__ b1v, const float* __restrict__ b2,
    const unsigned short* __restrict__ wf,
    const int*   __restrict__ cnt, const int* __restrict__ perm,
    unsigned short* __restrict__ xsh, unsigned short* __restrict__ xsl,
    float* __restrict__ out)
{
    const int bx = blockIdx.x, tid = threadIdx.x;
    const int lane = tid & 63, wave = tid >> 6;          // wave = n-tile (0..7)
    const int row16 = lane & 15, quad = lane >> 4;

    // block -> (module m, chunk) map from bucket counts; all static indexing
    int creg[MM];
    #pragma unroll
    for (int k = 0; k < MM; k++) creg[k] = cnt[t*MM + k];
    int m = -1, pref = 0, cm = 0, acc = 0;
    #pragma unroll
    for (int k = 0; k < MM; k++) {
        const int nbk = (creg[k] + TS - 1) >> 4;
        if (m < 0 && bx < acc + nbk) { m = k; pref = acc; cm = creg[k]; }
        acc += nbk;
    }
    if (m < 0) return;                                   // bx >= NB
    const int chunk = bx - pref;

    __shared__ __align__(16) unsigned short hfh[8][512]; // frag-linear A, hi
    __shared__ __align__(16) unsigned short hfl[8][512]; // lo
    __shared__ int   sids[TS];
    __shared__ float red[8][TS][CC];

    if (tid < TS) {
        const int sl = chunk*TS + tid;
        sids[tid] = (sl < cm) ? perm[((t*MM + m) << 12) + sl] : -1;
    }
    __syncthreads();

    const int sA  = sids[row16];
    const int sAc = sA < 0 ? 0 : sA;

    const unsigned short* xh_p = (t == 0 ? x0h : xsh) + (size_t)sAc*EE;
    const unsigned short* xl_p = (t == 0 ? x0l : xsl) + (size_t)sAc*EE;
    const unsigned short* eh_p = ebh + (size_t)t*BB*EE + (size_t)sAc*EE;
    const unsigned short* el_p = ebl + (size_t)t*BB*EE + (size_t)sAc*EE;

    bf16x8 xh[4], xl[4], eh[4], el_[4];
    #pragma unroll
    for (int kc = 0; kc < 4; kc++) {
        const int off = kc*32 + quad*8;
        xh[kc]  = *(const bf16x8*)(xh_p + off);
        xl[kc]  = *(const bf16x8*)(xl_p + off);
        eh[kc]  = *(const bf16x8*)(eh_p + off);
        el_[kc] = *(const bf16x8*)(el_p + off);
    }

    // phase 1: h_in, h_bi for this wave's 16 output cols
    f32x4 aci = {0.f,0.f,0.f,0.f}, acb = {0.f,0.f,0.f,0.f};
    #pragma unroll
    for (int kc = 0; kc < 4; kc++) {
        const unsigned short* bI = wf + (size_t)((m*8 + wave)*4 + kc)*FB;
        const unsigned short* bBp = wf + (size_t)(256 + (m*8 + wave)*4 + kc)*FB;
        const bf16x8 wih = *(const bf16x8*)(bI + lane*8);
        const bf16x8 wil = *(const bf16x8*)(bI + 512 + lane*8);
        const bf16x8 wbh = *(const bf16x8*)(bBp + lane*8);
        const bf16x8 wbl = *(const bf16x8*)(bBp + 512 + lane*8);
        aci = mfma3(xh[kc], xl[kc], wih, wil, aci);
        acb = mfma3(eh[kc], el_[kc], wbh, wbl, acb);
    }

    // epilogue 1: relu+bias, producer-side split, frag-linear LDS store
    {
        const int col = wave*16 + row16;
        const float bin = b_in [m*EE + col];
        const float bbi = b_bias[m*EE + col];
        #pragma unroll
        for (int r = 0; r < 4; r++) {
            const int row = quad*4 + r;
            {   // h_in -> k = col
                const float v = fmaxf(aci[r] + bin, 0.f);
                const int k = col, kc = k >> 5;
                const int idx = (row + 16*((k >> 3) & 3))*8 + (k & 7);
                split1(v, hfh[kc][idx], hfl[kc][idx]);
            }
            {   // h_bi -> k = 128 + col
                const float v = fmaxf(acb[r] + bbi, 0.f);
                const int k = EE + col, kc = k >> 5;
                const int idx = (row + 16*((k >> 3) & 3))*8 + (k & 7);
                split1(v, hfh[kc][idx], hfl[kc][idx]);
            }
        }
    }
    __syncthreads();

    // phase 2: x_new = tanh(h W_f + b_f), K = 256
    f32x4 acf = {0.f,0.f,0.f,0.f};
    #pragma unroll
    for (int kc = 0; kc < 8; kc++) {
        const bf16x8 ah = *(const bf16x8*)(&hfh[kc][lane*8]);
        const bf16x8 al = *(const bf16x8*)(&hfl[kc][lane*8]);
        const unsigned short* bF = wf + (size_t)(512 + (m*8 + wave)*8 + kc)*FB;
        const bf16x8 wfh = *(const bf16x8*)(bF + lane*8);
        const bf16x8 wfl = *(const bf16x8*)(bF + 512 + lane*8);
        acf = mfma3(ah, al, wfh, wfl, acf);
    }

    const int col = wave*16 + row16;
    const float bfv = b_f[m*EE + col];
    float xv[4];
    #pragma unroll
    for (int r = 0; r < 4; r++) xv[r] = tanhf(acf[r] + bfv);

    if (t < NSTEPS-1) {
        // write x_new for next step
        #pragma unroll
        for (int r = 0; r < 4; r++) {
            const int s = sids[quad*4 + r];
            if (s >= 0) {
                unsigned short h, l;
                split1(xv[r], h, l);
                xsh[(size_t)s*EE + col] = h;
                xsl[(size_t)s*EE + col] = l;
            }
        }
    } else {
        // ---- fused head: x stays on-chip ----
        __syncthreads();               // all waves done reading hf (phase 2)
        #pragma unroll
        for (int r = 0; r < 4; r++) {  // restage x split into hf kc 0..3
            const int row = quad*4 + r;
            const int k = col, kc = k >> 5;
            const int idx = (row + 16*((k >> 3) & 3))*8 + (k & 7);
            split1(xv[r], hfh[kc][idx], hfl[kc][idx]);
        }
        __syncthreads();

        // h = relu(x W1 + b1): 16 n-tiles, 2 per wave
        f32x4 a1[2] = {{0.f,0.f,0.f,0.f},{0.f,0.f,0.f,0.f}};
        #pragma unroll
        for (int i = 0; i < 2; i++) {
            const int nt = wave + 8*i;
            #pragma unroll
            for (int kc = 0; kc < 4; kc++) {
                const unsigned short* bW = wf + (size_t)(1024 + nt*4 + kc)*FB;
                const bf16x8 wh = *(const bf16x8*)(bW + lane*8);
                const bf16x8 wl = *(const bf16x8*)(bW + 512 + lane*8);
                const bf16x8 ah = *(const bf16x8*)(&hfh[kc][lane*8]);
                const bf16x8 al = *(const bf16x8*)(&hfl[kc][lane*8]);
                a1[i] = mfma3(ah, al, wh, wl, a1[i]);
            }
        }
        __syncthreads();               // done reading x-region before h overwrite
        #pragma unroll
        for (int i = 0; i < 2; i++) {
            const int c2 = (wave + 8*i)*16 + row16;      // 0..255
            const float b = b1v[c2];
            #pragma unroll
            for (int r = 0; r < 4; r++) {
                const int row = quad*4 + r;
                const float v = fmaxf(a1[i][r] + b, 0.f);
                const int kc = c2 >> 5;
                const int idx = (row + 16*((c2 >> 3) & 3))*8 + (c2 & 7);
                split1(v, hfh[kc][idx], hfl[kc][idx]);
            }
        }
        __syncthreads();

        // out = h W2 + b2: K-split, wave = kc
        f32x4 a2 = {0.f,0.f,0.f,0.f};
        {
            const int kc = wave;
            const bf16x8 ah = *(const bf16x8*)(&hfh[kc][lane*8]);
            const bf16x8 al = *(const bf16x8*)(&hfl[kc][lane*8]);
            const unsigned short* bW = wf + (size_t)(1088 + kc)*FB;
            const bf16x8 wh = *(const bf16x8*)(bW + lane*8);
            const bf16x8 wl = *(const bf16x8*)(bW + 512 + lane*8);
            a2 = mfma3(ah, al, wh, wl, a2);
        }
        #pragma unroll
        for (int r = 0; r < 4; r++) red[wave][quad*4 + r][row16] = a2[r];
        __syncthreads();

        if (tid < TS*CC) {
            const int sr = sids[tid >> 4];
            if (sr >= 0) {
                const int c = tid & 15;
                float v = b2[c];
                #pragma unroll
                for (int w = 0; w < 8; w++) v += red[w][tid >> 4][c];
                out[(size_t)sr*CC + c] = v;
            }
        }
    }
}

// ---------------------------------------------------------------------------
extern "C" void kernel_launch(void* const* d_in, const int* in_sizes, int n_in,
                              void* d_out, int out_size, void* d_ws, size_t ws_size,
                              hipStream_t stream) {
    const int*   entity_ids = (const int*)  d_in[0];
    const int*   module_ids = (const int*)  d_in[1];
    const float* embedding  = (const float*)d_in[2];
    const float* W_in   = (const float*)d_in[3];
    const float* b_in   = (const float*)d_in[4];
    const float* W_bias = (const float*)d_in[5];
    const float* b_bias = (const float*)d_in[6];
    const float* W_f    = (const float*)d_in[7];
    const float* b_f    = (const float*)d_in[8];
    const float* W1     = (const float*)d_in[9];
    const float* b1     = (const float*)d_in[10];
    const float* W2     = (const float*)d_in[11];
    const float* b2     = (const float*)d_in[12];
    float* out = (float*)d_out;

    char* ws = (char*)d_ws;
    int* cnt  = (int*)(ws + 0);                           // 96 B
    int* perm = (int*)(ws + 4096);                        // 3*8*4096*4 = 384 KB
    unsigned short* wfb = (unsigned short*)(ws + (1u<<20));     // 2.25 MB
    unsigned short* x0h = (unsigned short*)(ws + (4u<<20));     // 1 MB each
    unsigned short* x0l = (unsigned short*)(ws + (5u<<20));
    unsigned short* xsh = (unsigned short*)(ws + (6u<<20));
    unsigned short* xsl = (unsigned short*)(ws + (7u<<20));
    unsigned short* ebh = (unsigned short*)(ws + (8u<<20));     // 3 MB (t-major)
    unsigned short* ebl = (unsigned short*)(ws + (11u<<20));    // 3 MB

    hipMemsetAsync(cnt, 0, NSTEPS*MM*sizeof(int), stream);
    prep_kernel<<<PREP_GRID, 512, 0, stream>>>(entity_ids, module_ids, embedding,
                                               W_in, W_bias, W_f, W1, W2,
                                               wfb, x0h, x0l, ebh, ebl, cnt, perm);
    for (int t = 0; t < NSTEPS; t++) {
        step_kernel<<<NBMAX, 512, 0, stream>>>(t, x0h, x0l, ebh, ebl,
                                               b_in, b_bias, b_f, b1, b2,
                                               wfb, cnt, perm, xsh, xsl, out);
    }
}